// Round 11
// baseline (144.172 us; speedup 1.0000x reference)
//
#include <hip/hip_runtime.h>
#include <stdint.h>

#define NC13 507
#define NC26 2028
#define NC52 8112
#define NCAND 10647
#define NCANDP 10648      // padded record count (s26 starts at 508, s52 at 2536)
#define PB13 0
#define PB26 508
#define PB52 2536
#define KSEL 512
#define POOLCAP 768
#define POOLTGT 640
#define SUPW 17           // padded SUP row stride (17 coprime 32 -> conflict-free)
#define CMW 17            // padded class-mask stride
#define DECB 12           // decode blocks per image (8 s52 + 2 s26 + 2 s13)
#define HBINS 4096

// ---------------------------------------------------------------------------
// Key semantics (verified absmax 0.0 across rounds):
//   valid (xo>0):  bit63 | float_bits(xo)<<32 | (0x3FFF - n)   [digit>=0x800]
//   invalid     :  (0x3FFF - n)                                 [digit==0]
// Descending key order == (conf desc, index asc) of the reference exactly.
// Keys are stored at plane-major slot i (coalesced); the VALUE carries n.
// ---------------------------------------------------------------------------
__device__ __forceinline__ unsigned long long make_key(float xo, int n) {
    const unsigned long long low = (unsigned long long)(0x3FFFu - (unsigned)n);
    return (xo > 0.0f)
        ? ((1ull << 63) | ((unsigned long long)__float_as_uint(xo) << 32) | low)
        : low;
}

// float4 decode of 4 consecutive candidates; class loads in batches of 4 with
// 1-ahead prefetch; SoA outputs; valid-only global-atomic histogram.
__device__ __forceinline__ void decode4(
    const float* __restrict__ in, const float* __restrict__ anch,
    int b, int a, int hw, int HW, int Hdim, float ts,
    int nbase, int pbase,
    float* __restrict__ bb,                 // per-image SoA base (6 planes x NCANDP)
    unsigned long long* __restrict__ kb,    // per-image keys
    unsigned int* __restrict__ hb)          // per-image histogram
{
    const int HW4 = HW >> 2;
    const float4* p4 = reinterpret_cast<const float4*>(
        in + ((size_t)b * 255 + (size_t)a * 85) * HW + hw);

    const float4 txv = p4[0];
    const float4 tyv = p4[(size_t)HW4];
    const float4 twv = p4[(size_t)2 * HW4];
    const float4 thv = p4[(size_t)3 * HW4];
    const float4 xov = p4[(size_t)4 * HW4];

    float4 best = make_float4(-INFINITY, -INFINITY, -INFINITY, -INFINITY);
    int bx = 0, by = 0, bz = 0, bw4 = 0;

    float4 vb[4];
    #pragma unroll
    for (int j = 0; j < 4; ++j) vb[j] = p4[(size_t)(5 + j) * HW4];
    for (int cb = 0; cb < 20; ++cb) {
        float4 vn[4];
        if (cb < 19) {
            #pragma unroll
            for (int j = 0; j < 4; ++j) vn[j] = p4[(size_t)(9 + cb * 4 + j) * HW4];
        }
        #pragma unroll
        for (int j = 0; j < 4; ++j) {
            const int c = cb * 4 + j;          // strict > == first-max (jnp.argmax)
            if (vb[j].x > best.x) { best.x = vb[j].x; bx = c; }
            if (vb[j].y > best.y) { best.y = vb[j].y; by = c; }
            if (vb[j].z > best.z) { best.z = vb[j].z; bz = c; }
            if (vb[j].w > best.w) { best.w = vb[j].w; bw4 = c; }
        }
        #pragma unroll
        for (int j = 0; j < 4; ++j) vb[j] = vn[j];
    }

    // keys (coalesced, plane-major slot) + valid-only histogram
    const int i0 = pbase + a * HW + hw;          // multiple of 4
    const unsigned long long k0 = make_key(xov.x, nbase + (hw + 0) * 3 + a);
    const unsigned long long k1 = make_key(xov.y, nbase + (hw + 1) * 3 + a);
    const unsigned long long k2 = make_key(xov.z, nbase + (hw + 2) * 3 + a);
    const unsigned long long k3 = make_key(xov.w, nbase + (hw + 3) * 3 + a);
    kb[i0 + 0] = k0; kb[i0 + 1] = k1; kb[i0 + 2] = k2; kb[i0 + 3] = k3;
    if (xov.x > 0.f) atomicAdd(&hb[(unsigned)(k0 >> 52)], 1u);
    if (xov.y > 0.f) atomicAdd(&hb[(unsigned)(k1 >> 52)], 1u);
    if (xov.z > 0.f) atomicAdd(&hb[(unsigned)(k2 >> 52)], 1u);
    if (xov.w > 0.f) atomicAdd(&hb[(unsigned)(k3 >> 52)], 1u);

    // decode (identical arithmetic to verified rounds) -> SoA float4 stores
    const float aw = anch[2 * a], ah = anch[2 * a + 1];
    float4 X1v, Y1v, X2v, Y2v, CFv, CLv;
#define DECC(comp, j, bidx) { \
        const int hwj = hw + j; \
        const int hj = hwj / Hdim, wj = hwj - hj * Hdim; \
        const float sx = 1.0f / (1.0f + expf(-txv.comp)); \
        const float sy = 1.0f / (1.0f + expf(-tyv.comp)); \
        const float cf = 1.0f / (1.0f + expf(-xov.comp)); \
        const float cx = ((float)wj + sx) * ts; \
        const float cy = ((float)hj + sy) * ts; \
        const float bw = aw * expf(twv.comp); \
        const float bh = ah * expf(thv.comp); \
        X1v.comp = cx - bw * 0.5f; Y1v.comp = cy - bh * 0.5f; \
        X2v.comp = cx + bw * 0.5f; Y2v.comp = cy + bh * 0.5f; \
        CFv.comp = cf; CLv.comp = (float)bidx; }
    DECC(x, 0, bx) DECC(y, 1, by) DECC(z, 2, bz) DECC(w, 3, bw4)
#undef DECC
    *reinterpret_cast<float4*>(bb + (size_t)0 * NCANDP + i0) = X1v;
    *reinterpret_cast<float4*>(bb + (size_t)1 * NCANDP + i0) = Y1v;
    *reinterpret_cast<float4*>(bb + (size_t)2 * NCANDP + i0) = X2v;
    *reinterpret_cast<float4*>(bb + (size_t)3 * NCANDP + i0) = Y2v;
    *reinterpret_cast<float4*>(bb + (size_t)4 * NCANDP + i0) = CFv;
    *reinterpret_cast<float4*>(bb + (size_t)5 * NCANDP + i0) = CLv;
}

// ---------------------------------------------------------------------------
// Kernel A: streaming decode + keys + valid-only histogram. No LDS.
// grid (DECB, B), 256 threads. `hist` pre-zeroed via hipMemsetAsync.
// ---------------------------------------------------------------------------
__global__ __launch_bounds__(256, 3) void decode_kernel(
    const float* __restrict__ in13,
    const float* __restrict__ in26,
    const float* __restrict__ in52,
    const float* __restrict__ a13,
    const float* __restrict__ a26,
    const float* __restrict__ a52,
    float* __restrict__ boxesAll,
    unsigned long long* __restrict__ keys,
    unsigned int* __restrict__ hist)
{
    const int role = blockIdx.x;
    const int b = blockIdx.y;
    const int tid = threadIdx.x;
    float* bb = boxesAll + (size_t)b * 6 * NCANDP;
    unsigned long long* kb = keys + (size_t)b * NCANDP;
    unsigned int* hb = hist + (size_t)b * HBINS;

    if (role < 8) {                      // s52: 2028 float4-groups over 8 blocks
        const int idx4 = role * 256 + tid;
        if (idx4 < 3 * 676) {
            const int a = idx4 / 676, g = idx4 - a * 676;
            decode4(in52, a52, b, a, g * 4, 2704, 52, 8.f, NC13 + NC26, PB52,
                    bb, kb, hb);
        }
    } else if (role < 10) {              // s26: 507 float4-groups over 2 blocks
        const int idx4 = (role - 8) * 256 + tid;
        if (idx4 < 3 * 169) {
            const int a = idx4 / 169, g = idx4 - a * 169;
            decode4(in26, a26, b, a, g * 4, 676, 26, 16.f, NC13, PB26,
                    bb, kb, hb);
        }
    } else {                             // s13: 507 scalar over 2 blocks
        const int idx = (role - 10) * 256 + tid;
        if (idx < NC13) {
            const int HW = 169;
            const int a = idx / HW, hw = idx - a * HW;
            const int h = hw / 13, w = hw - h * 13;
            const float* p = in13 + ((size_t)b * 255 + (size_t)a * 85) * HW + hw;
            const float tx = p[0];
            const float ty = p[(size_t)HW];
            const float tw = p[(size_t)2 * HW];
            const float th = p[(size_t)3 * HW];
            const float xo = p[(size_t)4 * HW];
            float best = -INFINITY; int bi = 0;
            float vb[4];
            #pragma unroll
            for (int j = 0; j < 4; ++j) vb[j] = p[(size_t)(5 + j) * HW];
            for (int cb = 0; cb < 20; ++cb) {
                float vn[4];
                if (cb < 19) {
                    #pragma unroll
                    for (int j = 0; j < 4; ++j) vn[j] = p[(size_t)(9 + cb * 4 + j) * HW];
                }
                #pragma unroll
                for (int j = 0; j < 4; ++j) {
                    const int c = cb * 4 + j;
                    if (vb[j] > best) { best = vb[j]; bi = c; }
                }
                #pragma unroll
                for (int j = 0; j < 4; ++j) vb[j] = vn[j];
            }
            const int n = hw * 3 + a;                 // reference index (base 0)
            const unsigned long long k = make_key(xo, n);
            const int i = PB13 + a * HW + hw;
            kb[i] = k;
            if (xo > 0.f) atomicAdd(&hb[(unsigned)(k >> 52)], 1u);
            const float sx   = 1.0f / (1.0f + expf(-tx));
            const float sy   = 1.0f / (1.0f + expf(-ty));
            const float cf   = 1.0f / (1.0f + expf(-xo));
            const float cx = ((float)w + sx) * 32.f;
            const float cy = ((float)h + sy) * 32.f;
            const float bw = a13[2 * a] * expf(tw);
            const float bh = a13[2 * a + 1] * expf(th);
            bb[(size_t)0 * NCANDP + i] = cx - bw * 0.5f;
            bb[(size_t)1 * NCANDP + i] = cy - bh * 0.5f;
            bb[(size_t)2 * NCANDP + i] = cx + bw * 0.5f;
            bb[(size_t)3 * NCANDP + i] = cy + bh * 0.5f;
            bb[(size_t)4 * NCANDP + i] = cf;
            bb[(size_t)5 * NCANDP + i] = (float)bi;
        } else if (idx == NC13) {
            kb[507] = 0;                 // pad slot: below every real key
        }
    }
}

// ---------------------------------------------------------------------------
// Kernel B: per-image select (precomputed histogram) + NMS. 1024 threads.
// ---------------------------------------------------------------------------
struct SelS {
    unsigned int hist[HBINS];
    unsigned long long pool[POOLCAP];
};
struct NmsS {
    float X1[KSEL], Y1[KSEL], X2[KSEL], Y2[KSEL], AR[KSEL], CF[KSEL];
    int CLS[KSEL];
    unsigned int CM[80 * CMW];
    unsigned int SUP[KSEL * SUPW];
    unsigned int KEEP[16];
};

__global__ __launch_bounds__(1024) void selnms_kernel(
    const unsigned long long* __restrict__ keys,
    const unsigned int* __restrict__ hist,
    const float* __restrict__ boxesAll,
    float* __restrict__ out)
{
    constexpr size_t USZ = sizeof(SelS) > sizeof(NmsS) ? sizeof(SelS) : sizeof(NmsS);
    __shared__ __align__(16) char smem[USZ];
    __shared__ int selidxL[KSEL];
    __shared__ unsigned long long sh_prefix, sh_tmin;
    __shared__ int sh_krem, sh_shift, sh_brk, sh_V;
    __shared__ unsigned int sh_cnt;

    const int b = blockIdx.x;
    const int tid = threadIdx.x;
    const unsigned long long* kb = keys + (size_t)b * NCANDP;
    SelS& S = *reinterpret_cast<SelS*>(smem);

    // ---- load precomputed valid-only histogram ----
    {
        const unsigned int* gh = hist + (size_t)b * HBINS;
        for (int i = tid; i < HBINS; i += 1024) S.hist[i] = gh[i];
    }
    if (tid == 0) { sh_cnt = 0; sh_prefix = 0; sh_krem = KSEL; sh_shift = 52; sh_brk = 0; }
    __syncthreads();

    // ---- V = total valid; patch bin 0 only in the degenerate case ----
    if (tid < 64) {
        unsigned int s = 0;
        for (int q = 0; q < 64; ++q) s += S.hist[tid * 64 + q];
        #pragma unroll
        for (int off = 32; off; off >>= 1) s += __shfl_xor(s, off);
        if (tid == 0) sh_V = (int)s;
    }
    __syncthreads();
    if (tid == 0 && sh_V < KSEL) S.hist[0] += (unsigned)(NCAND - sh_V);
    __syncthreads();

    // ---- radix scan (first pass uses the precomputed histogram) ----
    while (true) {
        const int shift = sh_shift;
        const unsigned long long prefix = sh_prefix;
        const int krem = sh_krem;
        if (tid < 64) {
            unsigned int s = 0;
            for (int q = 0; q < 64; ++q) s += S.hist[tid * 64 + q];
            unsigned int suf = s;
            for (int off = 1; off < 64; off <<= 1) {
                const unsigned int v = __shfl_down(suf, off);
                if (tid + off < 64) suf += v;
            }
            const unsigned long long ball = __ballot(suf >= (unsigned)krem);
            const int lstar = 63 - __clzll(ball);
            const unsigned int base = (lstar < 63) ? __shfl(suf, lstar + 1) : 0u;
            const unsigned int wv = S.hist[lstar * 64 + (63 - tid)];
            unsigned int pv = wv;
            for (int off = 1; off < 64; off <<= 1) {
                const unsigned int v = __shfl_up(pv, off);
                if (tid >= (unsigned)off) pv += v;
            }
            const unsigned long long b2 = __ballot(base + pv >= (unsigned)krem);
            const int mstar = __ffsll(b2) - 1;
            const unsigned int pvm = __shfl(pv, mstar);
            const unsigned int wvm = __shfl(wv, mstar);
            if (tid == 0) {
                const int dstar = lstar * 64 + (63 - mstar);
                const unsigned long long np = (prefix << 12) | (unsigned long long)dstar;
                const int Albl = (int)(base + pvm - wvm);
                const int Cpool = (KSEL - krem) + Albl + (int)wvm;
                sh_prefix = np;
                sh_krem = krem - Albl;
                if (Cpool <= POOLTGT || shift == 4) {
                    sh_brk = 1;
                    sh_tmin = np << shift;
                } else {
                    sh_shift = shift - 12;
                }
            }
        }
        __syncthreads();
        if (sh_brk) break;

        // rare exact-refinement path: rebuild histogram at finer shift
        const int nshift = sh_shift;
        const unsigned long long nprefix = sh_prefix;
        for (int i = tid; i < HBINS; i += 1024) S.hist[i] = 0;
        __syncthreads();
        for (int i = tid; i < NCANDP; i += 1024) {
            const unsigned long long k = kb[i];
            if ((k >> (nshift + 12)) == nprefix)
                atomicAdd(&S.hist[(unsigned)((k >> nshift) & 0xFFFull)], 1u);
        }
        __syncthreads();
    }
    const unsigned long long tmin = sh_tmin;

    // ---- gather pool (single pass over coalesced keys) ----
    for (int i = tid; i < NCANDP; i += 1024) {
        const unsigned long long k = kb[i];
        if (k >= tmin) {
            const unsigned int p = atomicAdd(&sh_cnt, 1u);
            if (p < POOLCAP) S.pool[p] = k;
        }
    }
    __syncthreads();
    const int C = ((int)sh_cnt < POOLCAP) ? (int)sh_cnt : POOLCAP;

    // ---- exact rank (keys globally distinct) ----
    for (int p = tid; p < C; p += 1024) {
        const unsigned long long k = S.pool[p];
        int r = 0;
        for (int j = 0; j < C; ++j) r += (S.pool[j] > k) ? 1 : 0;
        if (r < KSEL) selidxL[r] = 0x3FFF - (int)(k & 0x3FFFull);
    }
    const int V = (sh_V < KSEL) ? sh_V : KSEL;   // valid is a prefix of ranks
    __syncthreads();

    // ======================= NMS phase =======================
    NmsS& M = *reinterpret_cast<NmsS*>(smem);
    const int t5 = tid & 511;
    const int half = tid >> 9;

    const int n = selidxL[t5];
    int nbase, HW, pb;
    if (n < NC13)             { nbase = 0;           HW = 169;  pb = PB13; }
    else if (n < NC13 + NC26) { nbase = NC13;        HW = 676;  pb = PB26; }
    else                      { nbase = NC13 + NC26; HW = 2704; pb = PB52; }
    const int within = n - nbase;
    const int hw = within / 3, a = within - 3 * hw;
    const int i = pb + a * HW + hw;

    if (half == 0) {
        const float* bbp = boxesAll + (size_t)b * 6 * NCANDP;
        const float x1 = bbp[(size_t)0 * NCANDP + i];
        const float y1 = bbp[(size_t)1 * NCANDP + i];
        const float x2 = bbp[(size_t)2 * NCANDP + i];
        const float y2 = bbp[(size_t)3 * NCANDP + i];
        M.X1[t5] = x1; M.Y1[t5] = y1; M.X2[t5] = x2; M.Y2[t5] = y2;
        M.AR[t5] = (x2 - x1) * (y2 - y1);
        M.CF[t5] = bbp[(size_t)4 * NCANDP + i];
        M.CLS[t5] = (int)bbp[(size_t)5 * NCANDP + i];
    }
    for (int q = tid; q < 80 * CMW; q += 1024) M.CM[q] = 0;
    __syncthreads();

    const float x1 = M.X1[t5], y1 = M.Y1[t5], x2 = M.X2[t5], y2 = M.Y2[t5];
    const float ar = M.AR[t5];
    const int ci = M.CLS[t5];
    if (half == 0) atomicOr(&M.CM[ci * CMW + (t5 >> 5)], 1u << (t5 & 31));
    __syncthreads();

    for (int wj = half * 8; wj < half * 8 + 8; ++wj) {
        unsigned int m = M.CM[ci * CMW + wj];
        unsigned int bits = 0;
        while (m) {
            const int bit = __ffs(m) - 1;
            m &= m - 1;
            const int j = wj * 32 + bit;
            const float iw = fminf(x2, M.X2[j]) - fmaxf(x1, M.X1[j]);
            const float ih = fminf(y2, M.Y2[j]) - fmaxf(y1, M.Y1[j]);
            if (iw > 0.0f && ih > 0.0f) {
                const float inter = iw * ih;
                if (inter > 0.3f * (ar + M.AR[j] - inter + 1e-9f))
                    bits |= (1u << bit);
            }
        }
        M.SUP[t5 * SUPW + wj] = bits;
    }
    __syncthreads();

    // sequential greedy scan (exact lax.scan semantics), wave 0 only
    if (tid < 64) {
        unsigned int keepw = 0;       // lanes 0..15 hold the 512-bit keep mask
        unsigned int buf[16];
        #pragma unroll
        for (int r = 0; r < 16; ++r)
            buf[r] = (tid < 16) ? M.SUP[r * SUPW + tid] : 0u;
        for (int g = 0; g < 32; ++g) {
            unsigned int nbuf[16] = {0};
            if (g < 31) {
                #pragma unroll
                for (int r = 0; r < 16; ++r)
                    nbuf[r] = (tid < 16) ? M.SUP[((g + 1) * 16 + r) * SUPW + tid] : 0u;
            }
            #pragma unroll
            for (int r = 0; r < 16; ++r) {
                const int ii = g * 16 + r;
                const bool anysup = __any((keepw & buf[r]) != 0u);
                const bool ki = (ii < V) && !anysup;
                if (ki && tid == (ii >> 5)) keepw |= (1u << (ii & 31));
            }
            #pragma unroll
            for (int r = 0; r < 16; ++r) buf[r] = nbuf[r];
        }
        if (tid < 16) M.KEEP[tid] = keepw;
    }
    __syncthreads();

    if (tid < 512) {
        const float kf = ((M.KEEP[t5 >> 5] >> (t5 & 31)) & 1u) ? 1.0f : 0.0f;
        float* dst = out + ((size_t)b * KSEL + t5) * 7;
        dst[0] = x1; dst[1] = y1; dst[2] = x2; dst[3] = y2;
        dst[4] = M.CF[t5]; dst[5] = (float)ci; dst[6] = kf;
    }
}

// ---------------------------------------------------------------------------
extern "C" void kernel_launch(void* const* d_in, const int* in_sizes, int n_in,
                              void* d_out, int out_size, void* d_ws, size_t ws_size,
                              hipStream_t stream)
{
    (void)n_in; (void)out_size; (void)ws_size;
    const float* in13 = (const float*)d_in[0];
    const float* in26 = (const float*)d_in[1];
    const float* in52 = (const float*)d_in[2];
    const float* a13  = (const float*)d_in[3];
    const float* a26  = (const float*)d_in[4];
    const float* a52  = (const float*)d_in[5];
    float* out = (float*)d_out;
    const int B = in_sizes[0] / (255 * 169);

    char* w = (char*)d_ws;
    unsigned long long* keys = (unsigned long long*)w;
    w += ((size_t)B * NCANDP * sizeof(unsigned long long) + 255) & ~(size_t)255;
    float* boxesAll = (float*)w;
    w += ((size_t)B * 6 * NCANDP * sizeof(float) + 255) & ~(size_t)255;
    unsigned int* hist = (unsigned int*)w;
    w += ((size_t)B * HBINS * sizeof(unsigned int) + 255) & ~(size_t)255;

    hipMemsetAsync(hist, 0, (size_t)B * HBINS * sizeof(unsigned int), stream);
    decode_kernel<<<dim3(DECB, B), 256, 0, stream>>>(
        in13, in26, in52, a13, a26, a52, boxesAll, keys, hist);
    selnms_kernel<<<dim3(B), 1024, 0, stream>>>(keys, hist, boxesAll, out);
}

// Round 12
// 94.950 us; speedup vs baseline: 1.5184x; 1.5184x over previous
//
#include <hip/hip_runtime.h>
#include <stdint.h>

#define NC13 507
#define NC26 2028
#define NC52 8112
#define NCAND 10647
#define NCANDP 10648      // padded plane-major records (pad slot at 507)
#define PB13 0
#define PB26 508
#define PB52 2536
#define KSEL 512
#define POOLCAP 768
#define POOLTGT 640
#define SUPW 17           // padded SUP row stride (17 coprime 32 -> conflict-free)
#define CMW 17            // padded class-mask stride
#define HBINS 4096

// ---------------------------------------------------------------------------
// Key semantics (verified absmax 0.0 across rounds):
//   valid (xo>0):  bit63 | float_bits(xo)<<32 | (0x3FFF - n)   [digit>=0x800]
//   invalid     :  (0x3FFF - n)                                 [digit==0]
// Descending key order == (conf desc, index asc) of the reference exactly.
// Keys stored at plane-major slot i (coalesced); the VALUE carries n.
// ---------------------------------------------------------------------------
__device__ __forceinline__ unsigned long long make_key(float xo, int n) {
    const unsigned long long low = (unsigned long long)(0x3FFFu - (unsigned)n);
    return (xo > 0.0f)
        ? ((1ull << 63) | ((unsigned long long)__float_as_uint(xo) << 32) | low)
        : low;
}

// ---------------------------------------------------------------------------
// Kernel 1: lightscore — read ONLY channels 0..4 (coalesced), decode geometry
// into SoA planes, emit keys + LDS-merged valid-only radix histogram.
// grid (ceil(NCANDP/256), B), 256 threads. hist pre-zeroed via memset.
// ---------------------------------------------------------------------------
__global__ __launch_bounds__(256) void lightscore_kernel(
    const float* __restrict__ in13,
    const float* __restrict__ in26,
    const float* __restrict__ in52,
    const float* __restrict__ a13,
    const float* __restrict__ a26,
    const float* __restrict__ a52,
    float* __restrict__ geo,
    unsigned long long* __restrict__ keys,
    unsigned int* __restrict__ hist)
{
    __shared__ unsigned int lh[HBINS];
    const int tid = threadIdx.x;
    const int b = blockIdx.y;
    for (int q = tid; q < HBINS; q += 256) lh[q] = 0;
    __syncthreads();

    const int i = blockIdx.x * 256 + tid;
    if (i < NCANDP) {
        if (i == 507) {
            keys[(size_t)b * NCANDP + 507] = 0ull;   // pad: below every real key
        } else {
            const float* in; const float* anch; int HW, Hdim, pb, nb; float ts;
            if (i < 507)       { in = in13; anch = a13; HW = 169;  Hdim = 13; ts = 32.f; pb = PB13; nb = 0; }
            else if (i < 2536) { in = in26; anch = a26; HW = 676;  Hdim = 26; ts = 16.f; pb = PB26; nb = NC13; }
            else               { in = in52; anch = a52; HW = 2704; Hdim = 52; ts = 8.f;  pb = PB52; nb = NC13 + NC26; }
            const int wi = i - pb;
            const int a = wi / HW, hw = wi - a * HW;
            const int h = hw / Hdim, w = hw - h * Hdim;
            const float* p = in + ((size_t)b * 255 + (size_t)a * 85) * HW + hw;
            const float tx = p[0];
            const float ty = p[(size_t)HW];
            const float tw = p[(size_t)2 * HW];
            const float th = p[(size_t)3 * HW];
            const float xo = p[(size_t)4 * HW];
            const int n = nb + hw * 3 + a;           // reference candidate index
            const unsigned long long k = make_key(xo, n);
            keys[(size_t)b * NCANDP + i] = k;
            if (xo > 0.f) atomicAdd(&lh[(unsigned)(k >> 52)], 1u);
            // decode (identical arithmetic to verified rounds)
            const float sx = 1.0f / (1.0f + expf(-tx));
            const float sy = 1.0f / (1.0f + expf(-ty));
            const float cf = 1.0f / (1.0f + expf(-xo));
            const float cx = ((float)w + sx) * ts;
            const float cy = ((float)h + sy) * ts;
            const float bw = anch[2 * a] * expf(tw);
            const float bh = anch[2 * a + 1] * expf(th);
            float* g = geo + (size_t)b * 5 * NCANDP;
            g[(size_t)0 * NCANDP + i] = cx - bw * 0.5f;
            g[(size_t)1 * NCANDP + i] = cy - bh * 0.5f;
            g[(size_t)2 * NCANDP + i] = cx + bw * 0.5f;
            g[(size_t)3 * NCANDP + i] = cy + bh * 0.5f;
            g[(size_t)4 * NCANDP + i] = cf;
        }
    }
    __syncthreads();
    unsigned int* hb = hist + (size_t)b * HBINS;
    for (int q = tid; q < HBINS; q += 256) {
        const unsigned int v = lh[q];
        if (v) atomicAdd(&hb[q], v);
    }
}

// ---------------------------------------------------------------------------
// Kernel 2: selgather — per-image exact top-512 from the precomputed
// histogram (verified R10/R11 logic). One block per image, 1024 threads.
// ---------------------------------------------------------------------------
struct SelS {
    unsigned int hist[HBINS];
    unsigned long long pool[POOLCAP];
};

__global__ __launch_bounds__(1024) void selgather_kernel(
    const unsigned long long* __restrict__ keys,
    const unsigned int* __restrict__ hist,
    int* __restrict__ selidx,
    int* __restrict__ selV)
{
    __shared__ __align__(16) SelS S;
    __shared__ unsigned long long sh_prefix, sh_tmin;
    __shared__ int sh_krem, sh_shift, sh_brk, sh_V;
    __shared__ unsigned int sh_cnt;

    const int b = blockIdx.x;
    const int tid = threadIdx.x;
    const unsigned long long* kb = keys + (size_t)b * NCANDP;

    {
        const unsigned int* gh = hist + (size_t)b * HBINS;
        for (int i = tid; i < HBINS; i += 1024) S.hist[i] = gh[i];
    }
    if (tid == 0) { sh_cnt = 0; sh_prefix = 0; sh_krem = KSEL; sh_shift = 52; sh_brk = 0; }
    __syncthreads();

    // V = total valid (valid-only histogram); patch bin 0 in degenerate case
    if (tid < 64) {
        unsigned int s = 0;
        for (int q = 0; q < 64; ++q) s += S.hist[tid * 64 + q];
        #pragma unroll
        for (int off = 32; off; off >>= 1) s += __shfl_xor(s, off);
        if (tid == 0) sh_V = (int)s;
    }
    __syncthreads();
    if (tid == 0 && sh_V < KSEL) S.hist[0] += (unsigned)(NCAND - sh_V);
    __syncthreads();

    while (true) {
        const int shift = sh_shift;
        const unsigned long long prefix = sh_prefix;
        const int krem = sh_krem;
        if (tid < 64) {
            unsigned int s = 0;
            for (int q = 0; q < 64; ++q) s += S.hist[tid * 64 + q];
            unsigned int suf = s;
            for (int off = 1; off < 64; off <<= 1) {
                const unsigned int v = __shfl_down(suf, off);
                if (tid + off < 64) suf += v;
            }
            const unsigned long long ball = __ballot(suf >= (unsigned)krem);
            const int lstar = 63 - __clzll(ball);
            const unsigned int base = (lstar < 63) ? __shfl(suf, lstar + 1) : 0u;
            const unsigned int wv = S.hist[lstar * 64 + (63 - tid)];
            unsigned int pv = wv;
            for (int off = 1; off < 64; off <<= 1) {
                const unsigned int v = __shfl_up(pv, off);
                if (tid >= (unsigned)off) pv += v;
            }
            const unsigned long long b2 = __ballot(base + pv >= (unsigned)krem);
            const int mstar = __ffsll(b2) - 1;
            const unsigned int pvm = __shfl(pv, mstar);
            const unsigned int wvm = __shfl(wv, mstar);
            if (tid == 0) {
                const int dstar = lstar * 64 + (63 - mstar);
                const unsigned long long np = (prefix << 12) | (unsigned long long)dstar;
                const int Albl = (int)(base + pvm - wvm);
                const int Cpool = (KSEL - krem) + Albl + (int)wvm;
                sh_prefix = np;
                sh_krem = krem - Albl;
                if (Cpool <= POOLTGT || shift == 4) {
                    sh_brk = 1;
                    sh_tmin = np << shift;
                } else {
                    sh_shift = shift - 12;
                }
            }
        }
        __syncthreads();
        if (sh_brk) break;

        // rare exact-refinement: rebuild histogram at finer shift from keys
        const int nshift = sh_shift;
        const unsigned long long nprefix = sh_prefix;
        for (int i = tid; i < HBINS; i += 1024) S.hist[i] = 0;
        __syncthreads();
        for (int i = tid; i < NCANDP; i += 1024) {
            const unsigned long long k = kb[i];
            if ((k >> (nshift + 12)) == nprefix)
                atomicAdd(&S.hist[(unsigned)((k >> nshift) & 0xFFFull)], 1u);
        }
        __syncthreads();
    }
    const unsigned long long tmin = sh_tmin;

    for (int i = tid; i < NCANDP; i += 1024) {
        const unsigned long long k = kb[i];
        if (k >= tmin) {
            const unsigned int p = atomicAdd(&sh_cnt, 1u);
            if (p < POOLCAP) S.pool[p] = k;
        }
    }
    __syncthreads();
    const int C = ((int)sh_cnt < POOLCAP) ? (int)sh_cnt : POOLCAP;

    for (int p = tid; p < C; p += 1024) {
        const unsigned long long k = S.pool[p];
        int r = 0;
        for (int j = 0; j < C; ++j) r += (S.pool[j] > k) ? 1 : 0;
        if (r < KSEL) selidx[(size_t)b * KSEL + r] = 0x3FFF - (int)(k & 0x3FFFull);
    }
    if (tid == 0) selV[b] = sh_V;
}

// ---------------------------------------------------------------------------
// Kernel 3: clsgather — ONE WAVE PER SELECTED BOX (verified R3 logic).
// Exact first-max argmax over the 80 class channels via monotone key.
// grid (KSEL/4, B), 256 threads (4 waves = 4 boxes per block).
// ---------------------------------------------------------------------------
__device__ __forceinline__ unsigned long long cls_key(float v, int c) {
    unsigned int u = __float_as_uint(v);
    u = (u & 0x80000000u) ? ~u : (u | 0x80000000u);   // order-preserving map
    return ((unsigned long long)u << 32) | (unsigned long long)(127 - c);
}

__global__ __launch_bounds__(256) void clsgather_kernel(
    const float* __restrict__ in13,
    const float* __restrict__ in26,
    const float* __restrict__ in52,
    const int* __restrict__ selidx,
    int* __restrict__ clsArr)
{
    const int lane = threadIdx.x & 63;
    const int r = blockIdx.x * 4 + (threadIdx.x >> 6);
    const int b = blockIdx.y;
    const int n = selidx[(size_t)b * KSEL + r];

    const float* in; int HW, loc;
    if (n < NC13)             { in = in13; HW = 169;  loc = n; }
    else if (n < NC13 + NC26) { in = in26; HW = 676;  loc = n - NC13; }
    else                      { in = in52; HW = 2704; loc = n - NC13 - NC26; }
    const int hw = loc / 3, a = loc - 3 * hw;
    const float* p = in + ((size_t)b * 255 + (size_t)a * 85) * HW + hw;

    const float v0 = p[(size_t)(5 + lane) * HW];                 // classes 0..63
    const float v1 = p[(size_t)(69 + (lane & 15)) * HW];         // classes 64..79 (dup x4)

    unsigned long long k = cls_key(v0, lane);
    {
        const unsigned long long k1 = cls_key(v1, 64 + (lane & 15));
        if (k1 > k) k = k1;
    }
    #pragma unroll
    for (int off = 32; off; off >>= 1) {
        const unsigned int hi = __shfl_xor((unsigned int)(k >> 32), off);
        const unsigned int lo = __shfl_xor((unsigned int)(k & 0xFFFFFFFFu), off);
        const unsigned long long o = ((unsigned long long)hi << 32) | lo;
        if (o > k) k = o;
    }
    if (lane == 0) clsArr[(size_t)b * KSEL + r] = 127 - (int)(k & 0x7Full);
}

// ---------------------------------------------------------------------------
// Kernel 4: NMS (verified body). One block per image, 512 threads.
// ---------------------------------------------------------------------------
__global__ __launch_bounds__(512) void nms_kernel(
    const float* __restrict__ geo,
    const int* __restrict__ clsArr,
    const int* __restrict__ selidx,
    const int* __restrict__ selV,
    float* __restrict__ out)
{
    __shared__ float X1[KSEL], Y1[KSEL], X2[KSEL], Y2[KSEL], AR[KSEL];
    __shared__ unsigned int CM[80 * CMW];
    __shared__ unsigned int SUP[KSEL * SUPW];
    __shared__ unsigned int KEEP[16];

    const int b = blockIdx.x;
    const int tid = threadIdx.x;

    const int n = selidx[(size_t)b * KSEL + tid];
    int pb, HW, nb;
    if (n < NC13)             { pb = PB13; HW = 169;  nb = 0; }
    else if (n < NC13 + NC26) { pb = PB26; HW = 676;  nb = NC13; }
    else                      { pb = PB52; HW = 2704; nb = NC13 + NC26; }
    const int loc = n - nb;
    const int hw = loc / 3, a = loc - 3 * hw;
    const int i = pb + a * HW + hw;

    const float* g = geo + (size_t)b * 5 * NCANDP;
    const float x1 = g[(size_t)0 * NCANDP + i];
    const float y1 = g[(size_t)1 * NCANDP + i];
    const float x2 = g[(size_t)2 * NCANDP + i];
    const float y2 = g[(size_t)3 * NCANDP + i];
    const float cf = g[(size_t)4 * NCANDP + i];
    const int ci = clsArr[(size_t)b * KSEL + tid];
    const float ar = (x2 - x1) * (y2 - y1);
    X1[tid] = x1; Y1[tid] = y1; X2[tid] = x2; Y2[tid] = y2; AR[tid] = ar;
    for (int q = tid; q < 80 * CMW; q += KSEL) CM[q] = 0;
    const int V0 = selV[b];
    const int V = (V0 < KSEL) ? V0 : KSEL;      // valid is a prefix of ranks
    __syncthreads();

    atomicOr(&CM[ci * CMW + (tid >> 5)], 1u << (tid & 31));
    __syncthreads();

    for (int wj = 0; wj < 16; ++wj) {
        unsigned int m = CM[ci * CMW + wj];
        unsigned int bits = 0;
        while (m) {
            const int bit = __ffs(m) - 1;
            m &= m - 1;
            const int j = wj * 32 + bit;
            const float iw = fminf(x2, X2[j]) - fmaxf(x1, X1[j]);
            const float ih = fminf(y2, Y2[j]) - fmaxf(y1, Y1[j]);
            if (iw > 0.0f && ih > 0.0f) {
                const float inter = iw * ih;
                if (inter > 0.3f * (ar + AR[j] - inter + 1e-9f))
                    bits |= (1u << bit);
            }
        }
        SUP[tid * SUPW + wj] = bits;
    }
    __syncthreads();

    // sequential greedy scan (exact lax.scan semantics), wave 0 only
    if (tid < 64) {
        unsigned int keepw = 0;       // lanes 0..15 hold the 512-bit keep mask
        unsigned int buf[16];
        #pragma unroll
        for (int q = 0; q < 16; ++q)
            buf[q] = (tid < 16) ? SUP[q * SUPW + tid] : 0u;
        for (int gg = 0; gg < 32; ++gg) {
            unsigned int nbuf[16] = {0};
            if (gg < 31) {
                #pragma unroll
                for (int q = 0; q < 16; ++q)
                    nbuf[q] = (tid < 16) ? SUP[((gg + 1) * 16 + q) * SUPW + tid] : 0u;
            }
            #pragma unroll
            for (int q = 0; q < 16; ++q) {
                const int ii = gg * 16 + q;
                const bool anysup = __any((keepw & buf[q]) != 0u);
                const bool ki = (ii < V) && !anysup;
                if (ki && tid == (ii >> 5)) keepw |= (1u << (ii & 31));
            }
            #pragma unroll
            for (int q = 0; q < 16; ++q) buf[q] = nbuf[q];
        }
        if (tid < 16) KEEP[tid] = keepw;
    }
    __syncthreads();

    const float kf = ((KEEP[tid >> 5] >> (tid & 31)) & 1u) ? 1.0f : 0.0f;
    float* dst = out + ((size_t)b * KSEL + tid) * 7;
    dst[0] = x1; dst[1] = y1; dst[2] = x2; dst[3] = y2;
    dst[4] = cf; dst[5] = (float)ci; dst[6] = kf;
}

// ---------------------------------------------------------------------------
extern "C" void kernel_launch(void* const* d_in, const int* in_sizes, int n_in,
                              void* d_out, int out_size, void* d_ws, size_t ws_size,
                              hipStream_t stream)
{
    (void)n_in; (void)out_size; (void)ws_size;
    const float* in13 = (const float*)d_in[0];
    const float* in26 = (const float*)d_in[1];
    const float* in52 = (const float*)d_in[2];
    const float* a13  = (const float*)d_in[3];
    const float* a26  = (const float*)d_in[4];
    const float* a52  = (const float*)d_in[5];
    float* out = (float*)d_out;
    const int B = in_sizes[0] / (255 * 169);

    char* w = (char*)d_ws;
    unsigned long long* keys = (unsigned long long*)w;
    w += ((size_t)B * NCANDP * sizeof(unsigned long long) + 255) & ~(size_t)255;
    float* geo = (float*)w;
    w += ((size_t)B * 5 * NCANDP * sizeof(float) + 255) & ~(size_t)255;
    unsigned int* hist = (unsigned int*)w;
    w += ((size_t)B * HBINS * sizeof(unsigned int) + 255) & ~(size_t)255;
    int* selidx = (int*)w;  w += ((size_t)B * KSEL * sizeof(int) + 255) & ~(size_t)255;
    int* selV   = (int*)w;  w += ((size_t)B * sizeof(int) + 255) & ~(size_t)255;
    int* clsArr = (int*)w;  w += ((size_t)B * KSEL * sizeof(int) + 255) & ~(size_t)255;

    hipMemsetAsync(hist, 0, (size_t)B * HBINS * sizeof(unsigned int), stream);
    lightscore_kernel<<<dim3((NCANDP + 255) / 256, B), 256, 0, stream>>>(
        in13, in26, in52, a13, a26, a52, geo, keys, hist);
    selgather_kernel<<<dim3(B), 1024, 0, stream>>>(keys, hist, selidx, selV);
    clsgather_kernel<<<dim3(KSEL / 4, B), 256, 0, stream>>>(
        in13, in26, in52, selidx, clsArr);
    nms_kernel<<<dim3(B), 512, 0, stream>>>(geo, clsArr, selidx, selV, out);
}